// Round 2
// baseline (152.676 us; speedup 1.0000x reference)
//
#include <hip/hip_runtime.h>

// AQLM dequant: codes [8192,1024,2] i32, codebooks [2,65536,1,8] f32,
// scales [8192,1,1,1] f32 -> out [8192,8192] f32.
// out[o, i*8+j] = (cb0[codes[o,i,0]][j] + cb1[codes[o,i,1]][j]) * scales[o]

#define O_GROUPS 8192
#define I_GROUPS 1024
#define CB_SIZE  65536
#define IG       8

typedef float f32x4 __attribute__((ext_vector_type(4)));
typedef int   i32x2 __attribute__((ext_vector_type(2)));

__global__ __launch_bounds__(256) void aqlm_dequant_kernel(
    const i32x2* __restrict__ codes,   // [O*I] pairs
    const f32x4* __restrict__ cb,      // [2*CB_SIZE*2] float4 view of codebooks
    const float* __restrict__ scales,  // [O]
    f32x4*       __restrict__ out)     // [O*I*2]
{
    const int idx = blockIdx.x * blockDim.x + threadIdx.x;  // (o,i) pair, exact grid
    const i32x2 c = codes[idx];
    const int o = idx >> 10;            // I_GROUPS = 1024
    const float s = scales[o];

    // codebook 0 entry: 32 B = two float4
    const size_t e0 = (size_t)c.x * 2;
    const size_t e1 = (size_t)(CB_SIZE + c.y) * 2;  // codebook 1 offset
    f32x4 a0 = cb[e0];
    f32x4 a1 = cb[e0 + 1];
    f32x4 b0 = cb[e1];
    f32x4 b1 = cb[e1 + 1];

    f32x4 r0 = (a0 + b0) * s;
    f32x4 r1 = (a1 + b1) * s;

    // nontemporal: don't let the 256 MiB output stream evict the 4 MiB
    // codebooks from L2 (gathers should stay cache-resident)
    __builtin_nontemporal_store(r0, &out[(size_t)idx * 2]);
    __builtin_nontemporal_store(r1, &out[(size_t)idx * 2 + 1]);
}

extern "C" void kernel_launch(void* const* d_in, const int* in_sizes, int n_in,
                              void* d_out, int out_size, void* d_ws, size_t ws_size,
                              hipStream_t stream) {
    const i32x2* codes  = (const i32x2*)d_in[0];
    const f32x4* cb     = (const f32x4*)d_in[1];
    const float* scales = (const float*)d_in[2];
    f32x4*       out    = (f32x4*)d_out;

    const int total = O_GROUPS * I_GROUPS;        // 8388608 threads
    const int block = 256;
    const int grid  = total / block;              // 32768, exact
    aqlm_dequant_kernel<<<grid, block, 0, stream>>>(codes, cb, scales, out);
}

// Round 3
// 145.179 us; speedup vs baseline: 1.0516x; 1.0516x over previous
//
#include <hip/hip_runtime.h>

// AQLM dequant: codes [8192,1024,2] i32, codebooks [2,65536,1,8] f32,
// scales [8192,1,1,1] f32 -> out [8192,8192] f32.
// out[o, i*8+j] = (cb0[codes[o,i,0]][j] + cb1[codes[o,i,1]][j]) * scales[o]
//
// Lane-pairing: 2 consecutive lanes handle one (o,i) group; each lane loads
// one 16B half of each 32B codebook entry. A wave64 gather instruction then
// covers 32 entries (lane pairs coalesce within a cache line) instead of 64
// distinct lines -> halves TA/L1 line transactions vs 1-thread-per-group.

#define O_GROUPS 8192
#define I_GROUPS 1024
#define CB_SIZE  65536

typedef float f32x4 __attribute__((ext_vector_type(4)));
typedef int   i32x2 __attribute__((ext_vector_type(2)));

__global__ __launch_bounds__(256) void aqlm_dequant_kernel(
    const i32x2* __restrict__ codes,   // [O*I] code pairs
    const f32x4* __restrict__ cb,      // [2*CB_SIZE*2] float4 view of codebooks
    const float* __restrict__ scales,  // [O]
    f32x4*       __restrict__ out)     // [O*I*2]
{
    const int idx = blockIdx.x * blockDim.x + threadIdx.x;  // 2 threads per group
    const int g = idx >> 1;            // group index (o,i)
    const int h = idx & 1;             // which 16B half of the 32B entry
    const int o = g >> 10;             // I_GROUPS = 1024

    // streaming read-once: nontemporal so codes don't evict codebooks from L2
    const i32x2 c = __builtin_nontemporal_load(&codes[g]);
    const float s = scales[o];

    f32x4 a = cb[(size_t)c.x * 2 + h];                 // codebook 0, half h
    f32x4 b = cb[((size_t)CB_SIZE + c.y) * 2 + h];     // codebook 1, half h

    f32x4 r = (a + b) * s;

    // nontemporal: 256 MiB output stream must not evict the 4 MiB codebooks
    __builtin_nontemporal_store(r, &out[(size_t)g * 2 + h]);
}

extern "C" void kernel_launch(void* const* d_in, const int* in_sizes, int n_in,
                              void* d_out, int out_size, void* d_ws, size_t ws_size,
                              hipStream_t stream) {
    const i32x2* codes  = (const i32x2*)d_in[0];
    const f32x4* cb     = (const f32x4*)d_in[1];
    const float* scales = (const float*)d_in[2];
    f32x4*       out    = (f32x4*)d_out;

    const int total = O_GROUPS * I_GROUPS * 2;    // 16777216 threads, 2 per group
    const int block = 256;
    const int grid  = total / block;              // 65536, exact
    aqlm_dequant_kernel<<<grid, block, 0, stream>>>(codes, cb, scales, out);
}

// Round 4
// 127.533 us; speedup vs baseline: 1.1971x; 1.1384x over previous
//
#include <hip/hip_runtime.h>

// AQLM dequant: codes [8192,1024,2] i32, codebooks [2,65536,1,8] f32,
// scales [8192,1,1,1] f32 -> out [8192,8192] f32.
// out[o, i*8+j] = (cb0[codes[o,i,0]][j] + cb1[codes[o,i,1]][j]) * scales[o]
//
// Structure:
//  - lane-pairing: 2 lanes per (o,i) group, each lane owns one 16B half of
//    the 32B codebook entries (pairs coalesce within a cache line).
//  - BATCH=4 slots per thread, fully unrolled with static indexing: 4
//    independent codes loads -> 8 independent gathers -> 4 stores. Gives
//    4x memory-level parallelism per wave (was 1 dependent chain/thread).

#define O_GROUPS 8192
#define I_GROUPS 1024
#define CB_SIZE  65536
#define BATCH    4

typedef float f32x4 __attribute__((ext_vector_type(4)));
typedef int   i32x2 __attribute__((ext_vector_type(2)));

__global__ __launch_bounds__(256) void aqlm_dequant_kernel(
    const i32x2* __restrict__ codes,   // [O*I] code pairs
    const f32x4* __restrict__ cb,      // [2*CB_SIZE*2] float4 view of codebooks
    const float* __restrict__ scales,  // [O]
    f32x4*       __restrict__ out)     // [O*I*2]  (slot-indexed)
{
    const int tid  = threadIdx.x;
    const int base = blockIdx.x * (256 * BATCH) + tid;  // slot index, coalesced per k

    int   slot[BATCH];
    i32x2 c[BATCH];
    // phase 1: issue all code loads (independent, streaming)
    #pragma unroll
    for (int k = 0; k < BATCH; ++k) {
        slot[k] = base + k * 256;
        c[k] = __builtin_nontemporal_load(&codes[slot[k] >> 1]);
    }

    // phase 2: issue all gathers (8 independent L2-resident loads)
    f32x4 a[BATCH], b[BATCH];
    #pragma unroll
    for (int k = 0; k < BATCH; ++k) {
        const int h = slot[k] & 1;
        a[k] = cb[(size_t)c[k].x * 2 + h];
        b[k] = cb[((size_t)CB_SIZE + c[k].y) * 2 + h];
    }

    // phase 3: combine + streaming store
    #pragma unroll
    for (int k = 0; k < BATCH; ++k) {
        const float s = scales[slot[k] >> 11];   // o = g >> 10, g = slot >> 1
        f32x4 r = (a[k] + b[k]) * s;
        __builtin_nontemporal_store(r, &out[slot[k]]);
    }
}

extern "C" void kernel_launch(void* const* d_in, const int* in_sizes, int n_in,
                              void* d_out, int out_size, void* d_ws, size_t ws_size,
                              hipStream_t stream) {
    const i32x2* codes  = (const i32x2*)d_in[0];
    const f32x4* cb     = (const f32x4*)d_in[1];
    const float* scales = (const float*)d_in[2];
    f32x4*       out    = (f32x4*)d_out;

    const int total_slots = O_GROUPS * I_GROUPS * 2;        // 16777216
    const int block = 256;
    const int grid  = total_slots / (block * BATCH);        // 16384, exact
    aqlm_dequant_kernel<<<grid, block, 0, stream>>>(codes, cb, scales, out);
}